// Round 1
// baseline (1865.537 us; speedup 1.0000x reference)
//
#include <hip/hip_runtime.h>

// Window attention, B=8 C=128 H=W=512 ws=8 -> 32768 windows of (S=64, C=128).
// bf16 MFMA path: QK^T and PV via v_mfma_f32_16x16x32_bf16, softmax fp32.
// One 256-thread block (4 waves) per window; wave w owns token rows 16w..16w+15.

#define HW_ 262144            // 512*512 plane per channel
#define IMG ((size_t)128 * HW_)

typedef __bf16 bf16x8 __attribute__((ext_vector_type(8)));
typedef float  f32x4  __attribute__((ext_vector_type(4)));

__device__ __forceinline__ unsigned short f2bf(float f) {
  unsigned int u = __float_as_uint(f);
  u += 0x7FFFu + ((u >> 16) & 1u);   // RNE; inputs are finite
  return (unsigned short)(u >> 16);
}
__device__ __forceinline__ unsigned int pack2(unsigned short a, unsigned short b) {
  return (unsigned int)a | ((unsigned int)b << 16);
}

__global__ __launch_bounds__(256, 3)
void winattn_kernel(const float* __restrict__ x, float* __restrict__ out) {
  // +8-element pads keep ds_read_b128 16B-aligned and bank-balanced (2-way max).
  __shared__ __align__(16) unsigned short sXw [64 * 136];   // [t][c]  17408 B
  __shared__ __align__(16) unsigned short sXwT[128 * 72];   // [c][t]  18432 B
  __shared__ __align__(16) unsigned short sP  [4 * 16 * 72];// per-wave P slice

  unsigned int bid  = blockIdx.x;
  // XCD swizzle: each of the 8 XCDs gets a contiguous run of windows so that
  // ww-adjacent windows (sharing 128B lines; each uses 32B) hit the same L2.
  unsigned int widx = (bid & 7u) * 4096u + (bid >> 3);
  unsigned int b    = widx >> 12;
  unsigned int hw   = (widx >> 6) & 63u;
  unsigned int ww   = widx & 63u;

  const float* src = x   + (size_t)b * IMG + (size_t)(hw * 8) * 512 + ww * 8;
  float*       dst = out + (size_t)b * IMG + (size_t)(hw * 8) * 512 + ww * 8;

  unsigned int tid = threadIdx.x;

  // ---- stage window into LDS (fp32 -> bf16), both layouts ----
  // pair index p -> channel pair c=2*(p>>4), hy=(p>>1)&7, g=p&1 (float4 within row)
  #pragma unroll
  for (int r = 0; r < 4; ++r) {
    unsigned int p  = (unsigned int)r * 256u + tid;
    unsigned int c  = (p >> 4) * 2u;
    unsigned int hy = (p >> 1) & 7u;
    unsigned int g  = p & 1u;
    const float4* q4 = reinterpret_cast<const float4*>(src + (size_t)c * HW_ + hy * 512 + g * 4);
    float4 va = q4[0];
    float4 vb = q4[HW_ / 4];          // channel c+1
    unsigned int t0 = hy * 8 + g * 4; // token = hy*8 + wx
    unsigned short a0=f2bf(va.x), a1=f2bf(va.y), a2=f2bf(va.z), a3=f2bf(va.w);
    unsigned short b0=f2bf(vb.x), b1=f2bf(vb.y), b2=f2bf(vb.z), b3=f2bf(vb.w);
    *reinterpret_cast<unsigned int*>(&sXw[(t0 + 0) * 136 + c]) = pack2(a0, b0);
    *reinterpret_cast<unsigned int*>(&sXw[(t0 + 1) * 136 + c]) = pack2(a1, b1);
    *reinterpret_cast<unsigned int*>(&sXw[(t0 + 2) * 136 + c]) = pack2(a2, b2);
    *reinterpret_cast<unsigned int*>(&sXw[(t0 + 3) * 136 + c]) = pack2(a3, b3);
    uint2 wa; wa.x = pack2(a0, a1); wa.y = pack2(a2, a3);
    uint2 wb; wb.x = pack2(b0, b1); wb.y = pack2(b2, b3);
    *reinterpret_cast<uint2*>(&sXwT[c * 72 + t0])       = wa;
    *reinterpret_cast<uint2*>(&sXwT[(c + 1) * 72 + t0]) = wb;
  }
  __syncthreads();

  unsigned int lane = tid & 63u;
  unsigned int w    = tid >> 6;      // wave id: owns rows 16w..16w+15
  unsigned int l15  = lane & 15u;
  unsigned int q    = lane >> 4;     // quad

  // ---- QK^T: attn tile row w (16x64), K=128 in 4 chunks of 32 ----
  f32x4 acc[4];
  #pragma unroll
  for (int j = 0; j < 4; ++j) { f32x4 z = {0.f, 0.f, 0.f, 0.f}; acc[j] = z; }

  const unsigned short* aPtr = &sXw[(16u * w + l15) * 136 + q * 8];
  const unsigned short* bPtr = &sXw[l15 * 136 + q * 8];
  #pragma unroll
  for (int kc = 0; kc < 4; ++kc) {
    bf16x8 af = *reinterpret_cast<const bf16x8*>(aPtr + kc * 32);
    #pragma unroll
    for (int j = 0; j < 4; ++j) {
      bf16x8 bfr = *reinterpret_cast<const bf16x8*>(bPtr + j * 16 * 136 + kc * 32);
      acc[j] = __builtin_amdgcn_mfma_f32_16x16x32_bf16(af, bfr, acc[j], 0, 0, 0);
    }
  }

  // ---- softmax over t (row s = 16w + 4q + r); C-layout: col=l15, row=4q+reg ----
  const float scale = 0.08838834764831845f; // 1/sqrt(128)
  #pragma unroll
  for (int r = 0; r < 4; ++r) {
    float a0 = acc[0][r] * scale, a1 = acc[1][r] * scale;
    float a2 = acc[2][r] * scale, a3 = acc[3][r] * scale;
    float m = fmaxf(fmaxf(a0, a1), fmaxf(a2, a3));
    m = fmaxf(m, __shfl_xor(m, 1));
    m = fmaxf(m, __shfl_xor(m, 2));
    m = fmaxf(m, __shfl_xor(m, 4));
    m = fmaxf(m, __shfl_xor(m, 8));
    float e0 = __expf(a0 - m), e1 = __expf(a1 - m);
    float e2 = __expf(a2 - m), e3 = __expf(a3 - m);
    float s = e0 + e1 + e2 + e3;
    s += __shfl_xor(s, 1);
    s += __shfl_xor(s, 2);
    s += __shfl_xor(s, 4);
    s += __shfl_xor(s, 8);
    float inv = 1.0f / s;
    unsigned int rowBase = (w * 16u + 4u * q + (unsigned int)r) * 72u;
    sP[rowBase +  0 + l15] = f2bf(e0 * inv);
    sP[rowBase + 16 + l15] = f2bf(e1 * inv);
    sP[rowBase + 32 + l15] = f2bf(e2 * inv);
    sP[rowBase + 48 + l15] = f2bf(e3 * inv);
  }
  // sP written/read by the same wave only; compiler orders DS ops via lgkmcnt.

  // ---- PV as out^T = XwT * P^T : A[m=c][k=t]=sXwT, B[k=t][n=s]=sP(row-major) ----
  // C-layout of out^T: row=channel, col=token -> coalesced-ish direct stores.
  f32x4 oacc[8];
  #pragma unroll
  for (int i2 = 0; i2 < 8; ++i2) { f32x4 z = {0.f, 0.f, 0.f, 0.f}; oacc[i2] = z; }

  const unsigned short* pPtr  = &sP[(w * 16u + l15) * 72 + q * 8];
  const unsigned short* xtPtr = &sXwT[l15 * 72 + q * 8];
  #pragma unroll
  for (int kc = 0; kc < 2; ++kc) {
    bf16x8 pf = *reinterpret_cast<const bf16x8*>(pPtr + kc * 32);
    #pragma unroll
    for (int i2 = 0; i2 < 8; ++i2) {
      bf16x8 xf = *reinterpret_cast<const bf16x8*>(xtPtr + i2 * 16 * 72 + kc * 32);
      oacc[i2] = __builtin_amdgcn_mfma_f32_16x16x32_bf16(xf, pf, oacc[i2], 0, 0, 0);
    }
  }

  // ---- store: lane has token s = 16w + l15, channels c = 16*i2 + 4q + r ----
  unsigned int s   = 16u * w + l15;
  unsigned int off = (s >> 3) * 512u + (s & 7u);
  #pragma unroll
  for (int i2 = 0; i2 < 8; ++i2) {
    #pragma unroll
    for (int r = 0; r < 4; ++r) {
      unsigned int c = 16u * (unsigned int)i2 + 4u * q + (unsigned int)r;
      dst[(size_t)c * HW_ + off] = oacc[i2][r];
    }
  }
}

extern "C" void kernel_launch(void* const* d_in, const int* in_sizes, int n_in,
                              void* d_out, int out_size, void* d_ws, size_t ws_size,
                              hipStream_t stream) {
  const float* x = (const float*)d_in[0];
  float* out = (float*)d_out;
  // 8 * 64 * 64 = 32768 windows, one block each.
  winattn_kernel<<<dim3(32768), dim3(256), 0, stream>>>(x, out);
}